// Round 3
// baseline (4141.485 us; speedup 1.0000x reference)
//
#include <hip/hip_runtime.h>
#include <math.h>

#define DD 256   // feature dim
#define KK 256   // clusters
#define CHUNK 2048

// ---- row squared-norm: one 64-lane wave per row (rows of length 256, float4/lane)
__global__ __launch_bounds__(256) void rowsq_kernel(const float* __restrict__ A,
                                                    float* __restrict__ out, int rows) {
    int gtid = blockIdx.x * 256 + threadIdx.x;
    int row  = gtid >> 6;
    int lane = threadIdx.x & 63;
    if (row >= rows) return;
    float4 v = *reinterpret_cast<const float4*>(A + (size_t)row * DD + lane * 4);
    float s = v.x*v.x + v.y*v.y + v.z*v.z + v.w*v.w;
    #pragma unroll
    for (int m = 32; m >= 1; m >>= 1) s += __shfl_xor(s, m);
    if (lane == 0) out[row] = s;
}

// ---- fused x@c^T + softmax, writes r to r_out, accumulates w (column sums)
// block = 256 threads, tile = 64 rows x 256 cols (all K in-block)
__global__ __launch_bounds__(256) void assign_kernel(
    const float* __restrict__ x, const float* __restrict__ c,
    const float* __restrict__ xx, const float* __restrict__ ccn,
    const float* __restrict__ log_tau, float* __restrict__ r_out,
    float* __restrict__ w, int N)
{
    __shared__ float xs[64][33];
    __shared__ float cs[256][33];
    __shared__ float wsum[256];
    const int tid = threadIdx.x;
    const int tx = tid & 31, ty = tid >> 5;
    const int r0 = blockIdx.x * 64;

    float acc[8][8];
    #pragma unroll
    for (int i = 0; i < 8; ++i)
        #pragma unroll
        for (int j = 0; j < 8; ++j) acc[i][j] = 0.f;

    for (int kk = 0; kk < DD; kk += 32) {
        #pragma unroll
        for (int s = 0; s < 2; ++s) {
            int idx = s * 256 + tid;      // 0..511  -> 64 rows x 8 float4
            int rr = idx >> 3, c4 = (idx & 7) << 2;
            int gr = r0 + rr;
            float4 v = make_float4(0.f, 0.f, 0.f, 0.f);
            if (gr < N) v = *reinterpret_cast<const float4*>(x + (size_t)gr * DD + kk + c4);
            xs[rr][c4+0] = v.x; xs[rr][c4+1] = v.y; xs[rr][c4+2] = v.z; xs[rr][c4+3] = v.w;
        }
        #pragma unroll
        for (int s = 0; s < 8; ++s) {
            int idx = s * 256 + tid;      // 0..2047 -> 256 rows x 8 float4
            int kr = idx >> 3, c4 = (idx & 7) << 2;
            float4 v = *reinterpret_cast<const float4*>(c + (size_t)kr * DD + kk + c4);
            cs[kr][c4+0] = v.x; cs[kr][c4+1] = v.y; cs[kr][c4+2] = v.z; cs[kr][c4+3] = v.w;
        }
        __syncthreads();
        #pragma unroll 4
        for (int d = 0; d < 32; ++d) {
            float xv[8], cv[8];
            #pragma unroll
            for (int i = 0; i < 8; ++i) xv[i] = xs[ty*8 + i][d];
            #pragma unroll
            for (int j = 0; j < 8; ++j) cv[j] = cs[tx + 32*j][d];
            #pragma unroll
            for (int i = 0; i < 8; ++i)
                #pragma unroll
                for (int j = 0; j < 8; ++j) acc[i][j] += xv[i] * cv[j];
        }
        __syncthreads();
    }

    const float tau = expf(log_tau[0]);
    float ccv[8];
    #pragma unroll
    for (int j = 0; j < 8; ++j) ccv[j] = ccn[tx + 32*j];
    float wpart[8];
    #pragma unroll
    for (int j = 0; j < 8; ++j) wpart[j] = 0.f;

    for (int i = 0; i < 8; ++i) {
        int gr = r0 + ty*8 + i;
        float xxv = (gr < N) ? xx[gr] : 0.f;
        float lg[8];
        float m = -1e30f;
        #pragma unroll
        for (int j = 0; j < 8; ++j) {
            float d2 = xxv + ccv[j] - 2.f * acc[i][j];
            lg[j] = -d2 / tau;
            m = fmaxf(m, lg[j]);
        }
        #pragma unroll
        for (int mk = 16; mk >= 1; mk >>= 1) m = fmaxf(m, __shfl_xor(m, mk));
        float e[8], ssum = 0.f;
        #pragma unroll
        for (int j = 0; j < 8; ++j) { e[j] = expf(lg[j] - m); ssum += e[j]; }
        #pragma unroll
        for (int mk = 16; mk >= 1; mk >>= 1) ssum += __shfl_xor(ssum, mk);
        if (gr < N) {
            #pragma unroll
            for (int j = 0; j < 8; ++j) {
                float rv = e[j] / ssum;
                r_out[(size_t)gr * KK + tx + 32*j] = rv;
                wpart[j] += rv;
            }
        }
    }

    wsum[tid] = 0.f;
    __syncthreads();
    #pragma unroll
    for (int j = 0; j < 8; ++j) atomicAdd(&wsum[tx + 32*j], wpart[j]);
    __syncthreads();
    atomicAdd(&w[tid], wsum[tid]);
}

// ---- c_num += r^T @ x  (split over N chunks, atomic accumulate)
// grid = 16 output tiles (64x64) x nchunks; block = 256 threads, 4x4 per thread
__global__ __launch_bounds__(256) void accum_kernel(
    const float* __restrict__ r, const float* __restrict__ x,
    float* __restrict__ c_num, int N)
{
    __shared__ float rs[32][65];    // [n][k]  32 x 64
    __shared__ float xs2[32][65];   // [n][d]  32 x 64
    const int tid = threadIdx.x;
    const int tx = tid & 15, ty = tid >> 4;
    const int tile = blockIdx.x & 15;
    const int chunk = blockIdx.x >> 4;
    const int k0 = (tile >> 2) * 64;
    const int d0 = (tile & 3) * 64;
    const int n0 = chunk * CHUNK;
    const int nend = min(n0 + CHUNK, N);

    float acc[4][4];
    #pragma unroll
    for (int i = 0; i < 4; ++i)
        #pragma unroll
        for (int j = 0; j < 4; ++j) acc[i][j] = 0.f;

    for (int n = n0; n < nend; n += 32) {
        #pragma unroll
        for (int s = 0; s < 2; ++s) {
            int idx = s * 256 + tid;          // 0..511 -> 32 rows x 16 float4 (64 floats)
            int rr = idx >> 4, c4 = (idx & 15) << 2;
            int gn = n + rr;
            float4 rv = make_float4(0.f,0.f,0.f,0.f), xv = make_float4(0.f,0.f,0.f,0.f);
            if (gn < nend) {
                rv = *reinterpret_cast<const float4*>(r + (size_t)gn * KK + k0 + c4);
                xv = *reinterpret_cast<const float4*>(x + (size_t)gn * DD + d0 + c4);
            }
            rs [rr][c4+0]=rv.x; rs [rr][c4+1]=rv.y; rs [rr][c4+2]=rv.z; rs [rr][c4+3]=rv.w;
            xs2[rr][c4+0]=xv.x; xs2[rr][c4+1]=xv.y; xs2[rr][c4+2]=xv.z; xs2[rr][c4+3]=xv.w;
        }
        __syncthreads();
        #pragma unroll 4
        for (int nn = 0; nn < 32; ++nn) {
            float rv[4], xv[4];
            #pragma unroll
            for (int i = 0; i < 4; ++i) rv[i] = rs[nn][ty*4 + i];
            #pragma unroll
            for (int j = 0; j < 4; ++j) xv[j] = xs2[nn][tx + 16*j];
            #pragma unroll
            for (int i = 0; i < 4; ++i)
                #pragma unroll
                for (int j = 0; j < 4; ++j) acc[i][j] += rv[i] * xv[j];
        }
        __syncthreads();
    }
    #pragma unroll
    for (int i = 0; i < 4; ++i)
        #pragma unroll
        for (int j = 0; j < 4; ++j)
            atomicAdd(&c_num[(size_t)(k0 + ty*4 + i) * DD + d0 + tx + 16*j], acc[i][j]);
}

// ---- new_c = c_num / (w + 1e-8); accumulate shift^2; c_num becomes c_new in place
__global__ __launch_bounds__(256) void update_kernel(float* __restrict__ c_num,
    const float* __restrict__ w, const float* __restrict__ c_cur,
    float* __restrict__ shift2)
{
    int idx = blockIdx.x * 256 + threadIdx.x;
    int k = idx >> 8;
    float nc = c_num[idx] / (w[k] + 1e-8f);
    float d = nc - c_cur[idx];
    c_num[idx] = nc;
    float s = d * d;
    #pragma unroll
    for (int m = 32; m >= 1; m >>= 1) s += __shfl_xor(s, m);
    __shared__ float red[4];
    int lane = threadIdx.x & 63, wv = threadIdx.x >> 6;
    if (lane == 0) red[wv] = s;
    __syncthreads();
    if (threadIdx.x == 0) atomicAdd(shift2, red[0] + red[1] + red[2] + red[3]);
}

// ---- c_cur = done_old ? c_cur : c_new   (done_old: read BEFORE flag update)
__global__ __launch_bounds__(256) void commit_kernel(const float* __restrict__ c_new,
    float* __restrict__ c_cur, const int* __restrict__ done)
{
    int idx = blockIdx.x * 256 + threadIdx.x;
    if (!(*done)) c_cur[idx] = c_new[idx];
}

// ---- done |= (shift < EPS); reset shift accumulator
__global__ void flag_kernel(float* shift2, int* done) {
    if (sqrtf(*shift2) < 1e-5f) *done = 1;
    *shift2 = 0.f;
}

// ---- final: sqdist -> logits/0.243 + gumbel -> softmax -> y
__global__ __launch_bounds__(256) void final_kernel(
    const float* __restrict__ x, const float* __restrict__ c,
    const float* __restrict__ xx, const float* __restrict__ ccn,
    const float* __restrict__ log_tau, const float* __restrict__ unif,
    float* __restrict__ y, int N)
{
    __shared__ float xs[64][33];
    __shared__ float cs[256][33];
    const int tid = threadIdx.x;
    const int tx = tid & 31, ty = tid >> 5;
    const int r0 = blockIdx.x * 64;

    float acc[8][8];
    #pragma unroll
    for (int i = 0; i < 8; ++i)
        #pragma unroll
        for (int j = 0; j < 8; ++j) acc[i][j] = 0.f;

    for (int kk = 0; kk < DD; kk += 32) {
        #pragma unroll
        for (int s = 0; s < 2; ++s) {
            int idx = s * 256 + tid;
            int rr = idx >> 3, c4 = (idx & 7) << 2;
            int gr = r0 + rr;
            float4 v = make_float4(0.f, 0.f, 0.f, 0.f);
            if (gr < N) v = *reinterpret_cast<const float4*>(x + (size_t)gr * DD + kk + c4);
            xs[rr][c4+0] = v.x; xs[rr][c4+1] = v.y; xs[rr][c4+2] = v.z; xs[rr][c4+3] = v.w;
        }
        #pragma unroll
        for (int s = 0; s < 8; ++s) {
            int idx = s * 256 + tid;
            int kr = idx >> 3, c4 = (idx & 7) << 2;
            float4 v = *reinterpret_cast<const float4*>(c + (size_t)kr * DD + kk + c4);
            cs[kr][c4+0] = v.x; cs[kr][c4+1] = v.y; cs[kr][c4+2] = v.z; cs[kr][c4+3] = v.w;
        }
        __syncthreads();
        #pragma unroll 4
        for (int d = 0; d < 32; ++d) {
            float xv[8], cv[8];
            #pragma unroll
            for (int i = 0; i < 8; ++i) xv[i] = xs[ty*8 + i][d];
            #pragma unroll
            for (int j = 0; j < 8; ++j) cv[j] = cs[tx + 32*j][d];
            #pragma unroll
            for (int i = 0; i < 8; ++i)
                #pragma unroll
                for (int j = 0; j < 8; ++j) acc[i][j] += xv[i] * cv[j];
        }
        __syncthreads();
    }

    const float tau = expf(log_tau[0]);
    float ccv[8];
    #pragma unroll
    for (int j = 0; j < 8; ++j) ccv[j] = ccn[tx + 32*j];

    for (int i = 0; i < 8; ++i) {
        int gr = r0 + ty*8 + i;
        float xxv = (gr < N) ? xx[gr] : 0.f;
        float z[8];
        float m = -1e30f;
        #pragma unroll
        for (int j = 0; j < 8; ++j) {
            float d2 = xxv + ccv[j] - 2.f * acc[i][j];
            float lg = -d2 / tau;
            float u = (gr < N) ? unif[(size_t)gr * KK + tx + 32*j] : 0.5f;
            float g = -logf(-logf(u));
            z[j] = lg / 0.243f + g;
            m = fmaxf(m, z[j]);
        }
        #pragma unroll
        for (int mk = 16; mk >= 1; mk >>= 1) m = fmaxf(m, __shfl_xor(m, mk));
        float e[8], ssum = 0.f;
        #pragma unroll
        for (int j = 0; j < 8; ++j) { e[j] = expf(z[j] - m); ssum += e[j]; }
        #pragma unroll
        for (int mk = 16; mk >= 1; mk >>= 1) ssum += __shfl_xor(ssum, mk);
        if (gr < N) {
            #pragma unroll
            for (int j = 0; j < 8; ++j)
                y[(size_t)gr * KK + tx + 32*j] = e[j] / ssum;
        }
    }
}

extern "C" void kernel_launch(void* const* d_in, const int* in_sizes, int n_in,
                              void* d_out, int out_size, void* d_ws, size_t ws_size,
                              hipStream_t stream)
{
    const float* x       = (const float*)d_in[0];
    const float* c_in    = (const float*)d_in[1];
    const float* log_tau = (const float*)d_in[2];
    const float* unif    = (const float*)d_in[3];
    float* y = (float*)d_out;
    const int N = in_sizes[0] / DD;

    float* ws = (float*)d_ws;
    size_t off = 0;
    float* xx     = ws + off; off += (size_t)((N + 63) & ~63);
    float* ccn    = ws + off; off += KK;
    float* c_cur  = ws + off; off += (size_t)KK * DD;
    float* c_num  = ws + off; off += (size_t)KK * DD;   // becomes c_new in place
    float* w      = ws + off; off += KK;                // MUST follow c_num (one memset)
    float* shift2 = ws + off; off += 1;
    int*   done   = (int*)(ws + off); off += 1;

    hipMemsetAsync(shift2, 0, 2 * sizeof(float), stream);   // shift2 + done
    hipMemcpyAsync(c_cur, c_in, (size_t)KK * DD * sizeof(float),
                   hipMemcpyDeviceToDevice, stream);
    rowsq_kernel<<<(N + 3) / 4, 256, 0, stream>>>(x, xx, N);

    const int nblk = (N + 63) / 64;
    const int nch  = (N + CHUNK - 1) / CHUNK;
    for (int it = 0; it < 10; ++it) {
        rowsq_kernel<<<64, 256, 0, stream>>>(c_cur, ccn, KK);
        hipMemsetAsync(c_num, 0, (size_t)(KK * DD + KK) * sizeof(float), stream);
        assign_kernel<<<nblk, 256, 0, stream>>>(x, c_cur, xx, ccn, log_tau, y, w, N);
        accum_kernel<<<16 * nch, 256, 0, stream>>>(y, x, c_num, N);
        update_kernel<<<KK * DD / 256, 256, 0, stream>>>(c_num, w, c_cur, shift2);
        commit_kernel<<<KK * DD / 256, 256, 0, stream>>>(c_num, c_cur, done);
        flag_kernel<<<1, 1, 0, stream>>>(shift2, done);
    }
    rowsq_kernel<<<64, 256, 0, stream>>>(c_cur, ccn, KK);
    final_kernel<<<nblk, 256, 0, stream>>>(x, c_cur, xx, ccn, log_tau, unif, y, N);
}

// Round 4
// 2938.021 us; speedup vs baseline: 1.4096x; 1.4096x over previous
//
#include <hip/hip_runtime.h>
#include <math.h>

#define DD 256   // feature dim
#define KK 256   // clusters
#define CHUNK 2048

typedef __bf16 bf16x8 __attribute__((ext_vector_type(8)));
typedef float  f32x4  __attribute__((ext_vector_type(4)));

__device__ __forceinline__ ushort bf16_rne(float f) {
    uint u = __float_as_uint(f);
    u += 0x7FFFu + ((u >> 16) & 1u);
    return (ushort)(u >> 16);
}
__device__ __forceinline__ void split_bf16(float f, ushort& h, ushort& l) {
    h = bf16_rne(f);
    float hf = __uint_as_float((uint)h << 16);
    l = bf16_rne(f - hf);
}

// ---- row squared-norm: one 64-lane wave per row (rows of length 256, float4/lane)
__global__ __launch_bounds__(256) void rowsq_kernel(const float* __restrict__ A,
                                                    float* __restrict__ out, int rows) {
    int gtid = blockIdx.x * 256 + threadIdx.x;
    int row  = gtid >> 6;
    int lane = threadIdx.x & 63;
    if (row >= rows) return;
    float4 v = *reinterpret_cast<const float4*>(A + (size_t)row * DD + lane * 4);
    float s = v.x*v.x + v.y*v.y + v.z*v.z + v.w*v.w;
    #pragma unroll
    for (int m = 32; m >= 1; m >>= 1) s += __shfl_xor(s, m);
    if (lane == 0) out[row] = s;
}

// ============================================================================
// MFMA core (shared structure): block = 256 thr = 4 waves; tile 64 rows x 256 cols.
// Wave w computes rows [16w,16w+16) x all 256 cols = 16 MFMA 16x16 tiles.
// Split-bf16: acc += x_hi*c_hi + x_lo*c_hi + x_hi*c_lo  (lo*lo dropped).
// A-frag: lane l holds x[16w + (l&15)][kk + 8*(l>>4) + j], j=0..7  (row-major, b128)
// B-frag: lane l holds c[16t + (l&15)][kk + 8*(l>>4) + j]          (row-major, b128)
// C-frag: value (row = 16w + 4*(l>>4) + rr, col = 16t + (l&15))    [m89 verified]
// ============================================================================

// ---- fused x@c^T (MFMA) + softmax -> r (fp32 [n][k]) + w column sums
__global__ __launch_bounds__(256) void assign_mfma(
    const float* __restrict__ x, const float* __restrict__ c,
    const float* __restrict__ xx, const float* __restrict__ ccn,
    const float* __restrict__ log_tau, float* __restrict__ r_out,
    float* __restrict__ wglob, int N)
{
    __shared__ ushort xs_h[64][40], xs_l[64][40];     // pad 40: 80B rows, 16B-aligned
    __shared__ ushort cs_h[256][40], cs_l[256][40];
    __shared__ float wsum[256];

    const int tid = threadIdx.x;
    const int w = tid >> 6, l = tid & 63;
    const int lx = l & 15, lg4 = l >> 4;
    const int r0 = blockIdx.x * 64;

    wsum[tid] = 0.f;

    f32x4 acc[16];
    #pragma unroll
    for (int t = 0; t < 16; ++t) acc[t] = (f32x4){0.f, 0.f, 0.f, 0.f};

    for (int kk = 0; kk < DD; kk += 32) {
        __syncthreads();
        #pragma unroll
        for (int s = 0; s < 2; ++s) {                 // x tile: 64 x 32
            int idx = s * 256 + tid;
            int rr = idx >> 3, c4 = (idx & 7) << 2;
            int gr = r0 + rr;
            float4 v = make_float4(0.f, 0.f, 0.f, 0.f);
            if (gr < N) v = *reinterpret_cast<const float4*>(x + (size_t)gr * DD + kk + c4);
            ushort h0,l0,h1,l1,h2,l2,h3,l3;
            split_bf16(v.x, h0, l0); split_bf16(v.y, h1, l1);
            split_bf16(v.z, h2, l2); split_bf16(v.w, h3, l3);
            *reinterpret_cast<ushort4*>(&xs_h[rr][c4]) = make_ushort4(h0, h1, h2, h3);
            *reinterpret_cast<ushort4*>(&xs_l[rr][c4]) = make_ushort4(l0, l1, l2, l3);
        }
        #pragma unroll
        for (int s = 0; s < 8; ++s) {                 // c tile: 256 x 32
            int idx = s * 256 + tid;
            int rr = idx >> 3, c4 = (idx & 7) << 2;
            float4 v = *reinterpret_cast<const float4*>(c + (size_t)rr * DD + kk + c4);
            ushort h0,l0,h1,l1,h2,l2,h3,l3;
            split_bf16(v.x, h0, l0); split_bf16(v.y, h1, l1);
            split_bf16(v.z, h2, l2); split_bf16(v.w, h3, l3);
            *reinterpret_cast<ushort4*>(&cs_h[rr][c4]) = make_ushort4(h0, h1, h2, h3);
            *reinterpret_cast<ushort4*>(&cs_l[rr][c4]) = make_ushort4(l0, l1, l2, l3);
        }
        __syncthreads();

        const int fb = lg4 << 3;
        const int ar = (w << 4) + lx;
        bf16x8 ah = *reinterpret_cast<const bf16x8*>(&xs_h[ar][fb]);
        bf16x8 al = *reinterpret_cast<const bf16x8*>(&xs_l[ar][fb]);
        #pragma unroll
        for (int t = 0; t < 16; ++t) {
            const int br = (t << 4) + lx;
            bf16x8 bh = *reinterpret_cast<const bf16x8*>(&cs_h[br][fb]);
            bf16x8 bl = *reinterpret_cast<const bf16x8*>(&cs_l[br][fb]);
            acc[t] = __builtin_amdgcn_mfma_f32_16x16x32_bf16(ah, bh, acc[t], 0, 0, 0);
            acc[t] = __builtin_amdgcn_mfma_f32_16x16x32_bf16(al, bh, acc[t], 0, 0, 0);
            acc[t] = __builtin_amdgcn_mfma_f32_16x16x32_bf16(ah, bl, acc[t], 0, 0, 0);
        }
    }

    const float tau = expf(log_tau[0]);
    float ccv[16];
    #pragma unroll
    for (int t = 0; t < 16; ++t) ccv[t] = ccn[(t << 4) + lx];
    float wacc[16];
    #pragma unroll
    for (int t = 0; t < 16; ++t) wacc[t] = 0.f;

    #pragma unroll
    for (int rr = 0; rr < 4; ++rr) {
        const int gr = r0 + (w << 4) + (lg4 << 2) + rr;
        const bool valid = gr < N;
        const float xxv = valid ? xx[gr] : 0.f;
        float lg[16], m = -1e30f;
        #pragma unroll
        for (int t = 0; t < 16; ++t) {
            float d2 = xxv + ccv[t] - 2.f * acc[t][rr];
            lg[t] = -d2 / tau;
            m = fmaxf(m, lg[t]);
        }
        #pragma unroll
        for (int mk = 8; mk >= 1; mk >>= 1) m = fmaxf(m, __shfl_xor(m, mk));
        float es = 0.f;
        #pragma unroll
        for (int t = 0; t < 16; ++t) { lg[t] = __expf(lg[t] - m); es += lg[t]; }
        #pragma unroll
        for (int mk = 8; mk >= 1; mk >>= 1) es += __shfl_xor(es, mk);
        const float rinv = 1.f / es;
        if (valid) {
            #pragma unroll
            for (int t = 0; t < 16; ++t) {
                float rv = lg[t] * rinv;
                r_out[(size_t)gr * KK + (t << 4) + lx] = rv;
                wacc[t] += rv;
            }
        }
    }

    #pragma unroll
    for (int t = 0; t < 16; ++t) {
        float s = wacc[t];
        s += __shfl_xor(s, 16);
        s += __shfl_xor(s, 32);
        if (l < 16) atomicAdd(&wsum[(t << 4) + lx], s);
    }
    __syncthreads();
    atomicAdd(&wglob[tid], wsum[tid]);
}

// ---- final: x@c^T (MFMA) -> logits/0.243 + gumbel -> softmax -> y
__global__ __launch_bounds__(256) void final_mfma(
    const float* __restrict__ x, const float* __restrict__ c,
    const float* __restrict__ xx, const float* __restrict__ ccn,
    const float* __restrict__ log_tau, const float* __restrict__ unif,
    float* __restrict__ y, int N)
{
    __shared__ ushort xs_h[64][40], xs_l[64][40];
    __shared__ ushort cs_h[256][40], cs_l[256][40];

    const int tid = threadIdx.x;
    const int w = tid >> 6, l = tid & 63;
    const int lx = l & 15, lg4 = l >> 4;
    const int r0 = blockIdx.x * 64;

    f32x4 acc[16];
    #pragma unroll
    for (int t = 0; t < 16; ++t) acc[t] = (f32x4){0.f, 0.f, 0.f, 0.f};

    for (int kk = 0; kk < DD; kk += 32) {
        __syncthreads();
        #pragma unroll
        for (int s = 0; s < 2; ++s) {
            int idx = s * 256 + tid;
            int rr = idx >> 3, c4 = (idx & 7) << 2;
            int gr = r0 + rr;
            float4 v = make_float4(0.f, 0.f, 0.f, 0.f);
            if (gr < N) v = *reinterpret_cast<const float4*>(x + (size_t)gr * DD + kk + c4);
            ushort h0,l0,h1,l1,h2,l2,h3,l3;
            split_bf16(v.x, h0, l0); split_bf16(v.y, h1, l1);
            split_bf16(v.z, h2, l2); split_bf16(v.w, h3, l3);
            *reinterpret_cast<ushort4*>(&xs_h[rr][c4]) = make_ushort4(h0, h1, h2, h3);
            *reinterpret_cast<ushort4*>(&xs_l[rr][c4]) = make_ushort4(l0, l1, l2, l3);
        }
        #pragma unroll
        for (int s = 0; s < 8; ++s) {
            int idx = s * 256 + tid;
            int rr = idx >> 3, c4 = (idx & 7) << 2;
            float4 v = *reinterpret_cast<const float4*>(c + (size_t)rr * DD + kk + c4);
            ushort h0,l0,h1,l1,h2,l2,h3,l3;
            split_bf16(v.x, h0, l0); split_bf16(v.y, h1, l1);
            split_bf16(v.z, h2, l2); split_bf16(v.w, h3, l3);
            *reinterpret_cast<ushort4*>(&cs_h[rr][c4]) = make_ushort4(h0, h1, h2, h3);
            *reinterpret_cast<ushort4*>(&cs_l[rr][c4]) = make_ushort4(l0, l1, l2, l3);
        }
        __syncthreads();

        const int fb = lg4 << 3;
        const int ar = (w << 4) + lx;
        bf16x8 ah = *reinterpret_cast<const bf16x8*>(&xs_h[ar][fb]);
        bf16x8 al = *reinterpret_cast<const bf16x8*>(&xs_l[ar][fb]);
        #pragma unroll
        for (int t = 0; t < 16; ++t) {
            const int br = (t << 4) + lx;
            bf16x8 bh = *reinterpret_cast<const bf16x8*>(&cs_h[br][fb]);
            bf16x8 bl = *reinterpret_cast<const bf16x8*>(&cs_l[br][fb]);
            acc[t] = __builtin_amdgcn_mfma_f32_16x16x32_bf16(ah, bh, acc[t], 0, 0, 0);
            acc[t] = __builtin_amdgcn_mfma_f32_16x16x32_bf16(al, bh, acc[t], 0, 0, 0);
            acc[t] = __builtin_amdgcn_mfma_f32_16x16x32_bf16(ah, bl, acc[t], 0, 0, 0);
        }
    }

    const float tau = expf(log_tau[0]);
    float ccv[16];
    #pragma unroll
    for (int t = 0; t < 16; ++t) ccv[t] = ccn[(t << 4) + lx];

    #pragma unroll
    for (int rr = 0; rr < 4; ++rr) {
        const int gr = r0 + (w << 4) + (lg4 << 2) + rr;
        const bool valid = gr < N;
        const float xxv = valid ? xx[gr] : 0.f;
        float z[16], m = -1e30f;
        #pragma unroll
        for (int t = 0; t < 16; ++t) {
            float d2 = xxv + ccv[t] - 2.f * acc[t][rr];
            float lgt = -d2 / tau;
            float u = valid ? unif[(size_t)gr * KK + (t << 4) + lx] : 0.5f;
            float g = -logf(-logf(u));
            z[t] = lgt / 0.243f + g;
            m = fmaxf(m, z[t]);
        }
        #pragma unroll
        for (int mk = 8; mk >= 1; mk >>= 1) m = fmaxf(m, __shfl_xor(m, mk));
        float es = 0.f;
        #pragma unroll
        for (int t = 0; t < 16; ++t) { z[t] = __expf(z[t] - m); es += z[t]; }
        #pragma unroll
        for (int mk = 8; mk >= 1; mk >>= 1) es += __shfl_xor(es, mk);
        const float rinv = 1.f / es;
        if (valid) {
            #pragma unroll
            for (int t = 0; t < 16; ++t)
                y[(size_t)gr * KK + (t << 4) + lx] = z[t] * rinv;
        }
    }
}

// ---- c_num += r^T @ x  (fp32, split over N chunks, atomic accumulate) — unchanged
__global__ __launch_bounds__(256) void accum_kernel(
    const float* __restrict__ r, const float* __restrict__ x,
    float* __restrict__ c_num, int N)
{
    __shared__ float rs[32][65];
    __shared__ float xs2[32][65];
    const int tid = threadIdx.x;
    const int tx = tid & 15, ty = tid >> 4;
    const int tile = blockIdx.x & 15;
    const int chunk = blockIdx.x >> 4;
    const int k0 = (tile >> 2) * 64;
    const int d0 = (tile & 3) * 64;
    const int n0 = chunk * CHUNK;
    const int nend = min(n0 + CHUNK, N);

    float acc[4][4];
    #pragma unroll
    for (int i = 0; i < 4; ++i)
        #pragma unroll
        for (int j = 0; j < 4; ++j) acc[i][j] = 0.f;

    for (int n = n0; n < nend; n += 32) {
        #pragma unroll
        for (int s = 0; s < 2; ++s) {
            int idx = s * 256 + tid;
            int rr = idx >> 4, c4 = (idx & 15) << 2;
            int gn = n + rr;
            float4 rv = make_float4(0.f,0.f,0.f,0.f), xv = make_float4(0.f,0.f,0.f,0.f);
            if (gn < nend) {
                rv = *reinterpret_cast<const float4*>(r + (size_t)gn * KK + k0 + c4);
                xv = *reinterpret_cast<const float4*>(x + (size_t)gn * DD + d0 + c4);
            }
            rs [rr][c4+0]=rv.x; rs [rr][c4+1]=rv.y; rs [rr][c4+2]=rv.z; rs [rr][c4+3]=rv.w;
            xs2[rr][c4+0]=xv.x; xs2[rr][c4+1]=xv.y; xs2[rr][c4+2]=xv.z; xs2[rr][c4+3]=xv.w;
        }
        __syncthreads();
        #pragma unroll 4
        for (int nn = 0; nn < 32; ++nn) {
            float rv[4], xv[4];
            #pragma unroll
            for (int i = 0; i < 4; ++i) rv[i] = rs[nn][ty*4 + i];
            #pragma unroll
            for (int j = 0; j < 4; ++j) xv[j] = xs2[nn][tx + 16*j];
            #pragma unroll
            for (int i = 0; i < 4; ++i)
                #pragma unroll
                for (int j = 0; j < 4; ++j) acc[i][j] += rv[i] * xv[j];
        }
        __syncthreads();
    }
    #pragma unroll
    for (int i = 0; i < 4; ++i)
        #pragma unroll
        for (int j = 0; j < 4; ++j)
            atomicAdd(&c_num[(size_t)(k0 + ty*4 + i) * DD + d0 + tx + 16*j], acc[i][j]);
}

// ---- new_c = c_num / (w + 1e-8); accumulate shift^2
__global__ __launch_bounds__(256) void update_kernel(float* __restrict__ c_num,
    const float* __restrict__ w, const float* __restrict__ c_cur,
    float* __restrict__ shift2)
{
    int idx = blockIdx.x * 256 + threadIdx.x;
    int k = idx >> 8;
    float nc = c_num[idx] / (w[k] + 1e-8f);
    float d = nc - c_cur[idx];
    c_num[idx] = nc;
    float s = d * d;
    #pragma unroll
    for (int m = 32; m >= 1; m >>= 1) s += __shfl_xor(s, m);
    __shared__ float red[4];
    int lane = threadIdx.x & 63, wv = threadIdx.x >> 6;
    if (lane == 0) red[wv] = s;
    __syncthreads();
    if (threadIdx.x == 0) atomicAdd(shift2, red[0] + red[1] + red[2] + red[3]);
}

// ---- c_cur = done_old ? c_cur : c_new
__global__ __launch_bounds__(256) void commit_kernel(const float* __restrict__ c_new,
    float* __restrict__ c_cur, const int* __restrict__ done)
{
    int idx = blockIdx.x * 256 + threadIdx.x;
    if (!(*done)) c_cur[idx] = c_new[idx];
}

// ---- done |= (shift < EPS); reset shift accumulator
__global__ void flag_kernel(float* shift2, int* done) {
    if (sqrtf(*shift2) < 1e-5f) *done = 1;
    *shift2 = 0.f;
}

extern "C" void kernel_launch(void* const* d_in, const int* in_sizes, int n_in,
                              void* d_out, int out_size, void* d_ws, size_t ws_size,
                              hipStream_t stream)
{
    const float* x       = (const float*)d_in[0];
    const float* c_in    = (const float*)d_in[1];
    const float* log_tau = (const float*)d_in[2];
    const float* unif    = (const float*)d_in[3];
    float* y = (float*)d_out;
    const int N = in_sizes[0] / DD;

    float* ws = (float*)d_ws;
    size_t off = 0;
    float* xx     = ws + off; off += (size_t)((N + 63) & ~63);
    float* ccn    = ws + off; off += KK;
    float* c_cur  = ws + off; off += (size_t)KK * DD;
    float* c_num  = ws + off; off += (size_t)KK * DD;   // becomes c_new in place
    float* w      = ws + off; off += KK;                // MUST follow c_num (one memset)
    float* shift2 = ws + off; off += 1;
    int*   done   = (int*)(ws + off); off += 1;

    hipMemsetAsync(shift2, 0, 2 * sizeof(float), stream);   // shift2 + done
    hipMemcpyAsync(c_cur, c_in, (size_t)KK * DD * sizeof(float),
                   hipMemcpyDeviceToDevice, stream);
    rowsq_kernel<<<(N + 3) / 4, 256, 0, stream>>>(x, xx, N);

    const int nblk = (N + 63) / 64;
    const int nch  = (N + CHUNK - 1) / CHUNK;
    for (int it = 0; it < 10; ++it) {
        rowsq_kernel<<<64, 256, 0, stream>>>(c_cur, ccn, KK);
        hipMemsetAsync(c_num, 0, (size_t)(KK * DD + KK) * sizeof(float), stream);
        assign_mfma<<<nblk, 256, 0, stream>>>(x, c_cur, xx, ccn, log_tau, y, w, N);
        accum_kernel<<<16 * nch, 256, 0, stream>>>(y, x, c_num, N);
        update_kernel<<<KK * DD / 256, 256, 0, stream>>>(c_num, w, c_cur, shift2);
        commit_kernel<<<KK * DD / 256, 256, 0, stream>>>(c_num, c_cur, done);
        flag_kernel<<<1, 1, 0, stream>>>(shift2, done);
    }
    rowsq_kernel<<<64, 256, 0, stream>>>(c_cur, ccn, KK);
    final_mfma<<<nblk, 256, 0, stream>>>(x, c_cur, xx, ccn, log_tau, unif, y, N);
}

// Round 6
// 2266.230 us; speedup vs baseline: 1.8275x; 1.2964x over previous
//
#include <hip/hip_runtime.h>
#include <math.h>

#define DD 256   // feature dim
#define KK 256   // clusters
#define CHUNK 2048   // legacy fp32 accum chunking (fallback path)

typedef __bf16 bf16x8 __attribute__((ext_vector_type(8)));
typedef float  f32x4  __attribute__((ext_vector_type(4)));
typedef unsigned short ushort8 __attribute__((ext_vector_type(8)));

__device__ __forceinline__ ushort bf16_rne(float f) {
    uint u = __float_as_uint(f);
    u += 0x7FFFu + ((u >> 16) & 1u);
    return (ushort)(u >> 16);
}
// trunc-hi / rne-lo split: hi = top 16 bits, lo = rne(f - hi). residual ~2^-15 rel.
__device__ __forceinline__ void split2(float f, ushort& h, ushort& l) {
    uint u = __float_as_uint(f);
    h = (ushort)(u >> 16);
    float hf = __uint_as_float(u & 0xFFFF0000u);
    l = bf16_rne(f - hf);
}

// ---- row squared-norm for x: one 64-lane wave per row
__global__ __launch_bounds__(256) void rowsq_kernel(const float* __restrict__ A,
                                                    float* __restrict__ out, int rows) {
    int gtid = blockIdx.x * 256 + threadIdx.x;
    int row  = gtid >> 6;
    int lane = threadIdx.x & 63;
    if (row >= rows) return;
    float4 v = *reinterpret_cast<const float4*>(A + (size_t)row * DD + lane * 4);
    float s = v.x*v.x + v.y*v.y + v.z*v.z + v.w*v.w;
    #pragma unroll
    for (int m = 32; m >= 1; m >>= 1) s += __shfl_xor(s, m);
    if (lane == 0) out[row] = s;
}

// ---- one-time: x [N][256] f32 -> xT_h/xT_l [256][NPAD] bf16 (transposed + split)
// block covers 64 n-rows; wave w handles d-float4-groups w*16..w*16+15; lane = n.
__global__ __launch_bounds__(256) void xtrans_kernel(const float* __restrict__ x,
    ushort* __restrict__ xT_h, ushort* __restrict__ xT_l, int N, int NPAD)
{
    const int n0 = blockIdx.x * 64;
    const int w = threadIdx.x >> 6, l = threadIdx.x & 63;
    const int n = n0 + l;
    #pragma unroll 4
    for (int g = w * 16; g < w * 16 + 16; ++g) {
        float4 v = make_float4(0.f, 0.f, 0.f, 0.f);
        if (n < N) v = *reinterpret_cast<const float4*>(x + (size_t)n * DD + g * 4);
        float vv[4] = {v.x, v.y, v.z, v.w};
        #pragma unroll
        for (int i = 0; i < 4; ++i) {
            ushort h, lo; split2(vv[i], h, lo);
            xT_h[(size_t)(g * 4 + i) * NPAD + n] = h;   // 64 lanes -> 128B coalesced
            xT_l[(size_t)(g * 4 + i) * NPAD + n] = lo;
        }
    }
}

// ---- c [256][256] f32 -> c_h/c_l bf16 + ccn row-norms (pre-loop; loop uses fusedupd)
__global__ __launch_bounds__(256) void csplit_kernel(const float* __restrict__ c,
    ushort* __restrict__ c_h, ushort* __restrict__ c_l, float* __restrict__ ccn)
{
    const int w = threadIdx.x >> 6, l = threadIdx.x & 63;
    const int row = blockIdx.x * 4 + w;
    float4 v = *reinterpret_cast<const float4*>(c + (size_t)row * DD + l * 4);
    float vv[4] = {v.x, v.y, v.z, v.w};
    ushort h[4], lo[4];
    #pragma unroll
    for (int i = 0; i < 4; ++i) split2(vv[i], h[i], lo[i]);
    *reinterpret_cast<ushort4*>(c_h + (size_t)row * DD + l * 4) = make_ushort4(h[0], h[1], h[2], h[3]);
    *reinterpret_cast<ushort4*>(c_l + (size_t)row * DD + l * 4) = make_ushort4(lo[0], lo[1], lo[2], lo[3]);
    float s = v.x*v.x + v.y*v.y + v.z*v.z + v.w*v.w;
    #pragma unroll
    for (int m = 32; m >= 1; m >>= 1) s += __shfl_xor(s, m);
    if (l == 0) ccn[row] = s;
}

// ============================================================================
// assign: x@c^T (MFMA split-bf16 3-pass) + softmax -> r (f32) + w col sums.
// block 256 thr = 4 waves; tile 64 rows x 256 cols; c staged from pre-split c_h/c_l.
// ============================================================================
__global__ __launch_bounds__(256) void assign_mfma(
    const float* __restrict__ x, const ushort* __restrict__ c_h,
    const ushort* __restrict__ c_l, const float* __restrict__ xx,
    const float* __restrict__ ccn, const float* __restrict__ log_tau,
    float* __restrict__ r_out, float* __restrict__ wglob, int N)
{
    __shared__ ushort xs_h[64][40], xs_l[64][40];
    __shared__ ushort cs_h[256][40], cs_l[256][40];
    __shared__ float wsum[256];

    const int tid = threadIdx.x;
    const int w = tid >> 6, l = tid & 63;
    const int lx = l & 15, lg4 = l >> 4;
    const int r0 = blockIdx.x * 64;

    wsum[tid] = 0.f;

    f32x4 acc[16];
    #pragma unroll
    for (int t = 0; t < 16; ++t) acc[t] = (f32x4){0.f, 0.f, 0.f, 0.f};

    for (int kk = 0; kk < DD; kk += 32) {
        __syncthreads();
        #pragma unroll
        for (int s = 0; s < 2; ++s) {                 // x tile 64x32: f32 + split
            int idx = s * 256 + tid;
            int rr = idx >> 3, c4 = (idx & 7) << 2;
            int gr = r0 + rr;
            float4 v = make_float4(0.f, 0.f, 0.f, 0.f);
            if (gr < N) v = *reinterpret_cast<const float4*>(x + (size_t)gr * DD + kk + c4);
            ushort h0,l0,h1,l1,h2,l2,h3,l3;
            split2(v.x, h0, l0); split2(v.y, h1, l1);
            split2(v.z, h2, l2); split2(v.w, h3, l3);
            *reinterpret_cast<ushort4*>(&xs_h[rr][c4]) = make_ushort4(h0, h1, h2, h3);
            *reinterpret_cast<ushort4*>(&xs_l[rr][c4]) = make_ushort4(l0, l1, l2, l3);
        }
        #pragma unroll
        for (int s = 0; s < 4; ++s) {                 // c tile 256x32: ushort8 copies
            int idx = s * 256 + tid;
            int rr = idx >> 2, c8 = (idx & 3) << 3;
            *reinterpret_cast<ushort8*>(&cs_h[rr][c8]) =
                *reinterpret_cast<const ushort8*>(c_h + (size_t)rr * DD + kk + c8);
            *reinterpret_cast<ushort8*>(&cs_l[rr][c8]) =
                *reinterpret_cast<const ushort8*>(c_l + (size_t)rr * DD + kk + c8);
        }
        __syncthreads();

        const int fb = lg4 << 3;
        const int ar = (w << 4) + lx;
        bf16x8 ah = *reinterpret_cast<const bf16x8*>(&xs_h[ar][fb]);
        bf16x8 al = *reinterpret_cast<const bf16x8*>(&xs_l[ar][fb]);
        #pragma unroll
        for (int t = 0; t < 16; ++t) {
            const int br = (t << 4) + lx;
            bf16x8 bh = *reinterpret_cast<const bf16x8*>(&cs_h[br][fb]);
            bf16x8 bl = *reinterpret_cast<const bf16x8*>(&cs_l[br][fb]);
            acc[t] = __builtin_amdgcn_mfma_f32_16x16x32_bf16(ah, bh, acc[t], 0, 0, 0);
            acc[t] = __builtin_amdgcn_mfma_f32_16x16x32_bf16(al, bh, acc[t], 0, 0, 0);
            acc[t] = __builtin_amdgcn_mfma_f32_16x16x32_bf16(ah, bl, acc[t], 0, 0, 0);
        }
    }

    const float tau = expf(log_tau[0]);
    float ccv[16];
    #pragma unroll
    for (int t = 0; t < 16; ++t) ccv[t] = ccn[(t << 4) + lx];
    float wacc[16];
    #pragma unroll
    for (int t = 0; t < 16; ++t) wacc[t] = 0.f;

    #pragma unroll
    for (int rr = 0; rr < 4; ++rr) {
        const int gr = r0 + (w << 4) + (lg4 << 2) + rr;
        const bool valid = gr < N;
        const float xxv = valid ? xx[gr] : 0.f;
        float lg[16], m = -1e30f;
        #pragma unroll
        for (int t = 0; t < 16; ++t) {
            float d2 = xxv + ccv[t] - 2.f * acc[t][rr];
            lg[t] = -d2 / tau;
            m = fmaxf(m, lg[t]);
        }
        #pragma unroll
        for (int mk = 8; mk >= 1; mk >>= 1) m = fmaxf(m, __shfl_xor(m, mk));
        float es = 0.f;
        #pragma unroll
        for (int t = 0; t < 16; ++t) { lg[t] = __expf(lg[t] - m); es += lg[t]; }
        #pragma unroll
        for (int mk = 8; mk >= 1; mk >>= 1) es += __shfl_xor(es, mk);
        const float rinv = 1.f / es;
        if (valid) {
            #pragma unroll
            for (int t = 0; t < 16; ++t) {
                float rv = lg[t] * rinv;
                r_out[(size_t)gr * KK + (t << 4) + lx] = rv;
                wacc[t] += rv;
            }
        }
    }

    #pragma unroll
    for (int t = 0; t < 16; ++t) {
        float s = wacc[t];
        s += __shfl_xor(s, 16);
        s += __shfl_xor(s, 32);
        if (l < 16) atomicAdd(&wsum[(t << 4) + lx], s);
    }
    __syncthreads();
    atomicAdd(&wglob[tid], wsum[tid]);
}

// ============================================================================
// accum: c_num += r^T @ x via MFMA. Grid = 4 k-strips x nchunks (384 n each).
// Block: 64 k x 256 d output; wave w owns k rows [16w,16w+16), 16 d-tiles.
// r staged f32->split->transposed u16 scatter (small); x staged from pre-split xT.
// ============================================================================
__global__ __launch_bounds__(256) void accum_mfma(
    const float* __restrict__ r, const ushort* __restrict__ xT_h,
    const ushort* __restrict__ xT_l, float* __restrict__ c_num, int N, int NPAD)
{
    __shared__ ushort rT_h[64][40], rT_l[64][40];     // [k][n] transposed
    __shared__ ushort xs_h[256][40], xs_l[256][40];   // [d][n] (from xT: no transpose)

    const int tid = threadIdx.x;
    const int w = tid >> 6, l = tid & 63;
    const int lx = l & 15, lg4 = l >> 4;
    const int strip = blockIdx.x & 3;
    const int chunk = blockIdx.x >> 2;
    const int kb0 = strip * 64;
    const int n0c = chunk * 384;
    const int nend = min(n0c + 384, N);

    f32x4 acc[16];
    #pragma unroll
    for (int t = 0; t < 16; ++t) acc[t] = (f32x4){0.f, 0.f, 0.f, 0.f};

    for (int n0 = n0c; n0 < nend; n0 += 32) {
        __syncthreads();
        #pragma unroll
        for (int s = 0; s < 2; ++s) {                 // r tile 32n x 64k, transpose
            int idx = s * 256 + tid;
            int nn = idx >> 4, k4 = (idx & 15) << 2;
            int gn = n0 + nn;
            float4 v = make_float4(0.f, 0.f, 0.f, 0.f);
            if (gn < N) v = *reinterpret_cast<const float4*>(r + (size_t)gn * KK + kb0 + k4);
            float vv[4] = {v.x, v.y, v.z, v.w};
            #pragma unroll
            for (int i = 0; i < 4; ++i) {
                ushort h, lo; split2(vv[i], h, lo);
                rT_h[k4 + i][nn] = h;
                rT_l[k4 + i][nn] = lo;
            }
        }
        #pragma unroll
        for (int s = 0; s < 4; ++s) {                 // x tile 256d x 32n: pure copies
            int idx = s * 256 + tid;
            int dd = idx >> 2, ng = (idx & 3) << 3;
            *reinterpret_cast<ushort8*>(&xs_h[dd][ng]) =
                *reinterpret_cast<const ushort8*>(xT_h + (size_t)dd * NPAD + n0 + ng);
            *reinterpret_cast<ushort8*>(&xs_l[dd][ng]) =
                *reinterpret_cast<const ushort8*>(xT_l + (size_t)dd * NPAD + n0 + ng);
        }
        __syncthreads();

        const int fb = lg4 << 3;
        bf16x8 ah = *reinterpret_cast<const bf16x8*>(&rT_h[(w << 4) + lx][fb]);
        bf16x8 al = *reinterpret_cast<const bf16x8*>(&rT_l[(w << 4) + lx][fb]);
        #pragma unroll
        for (int t = 0; t < 16; ++t) {
            const int br = (t << 4) + lx;
            bf16x8 bh = *reinterpret_cast<const bf16x8*>(&xs_h[br][fb]);
            bf16x8 bl = *reinterpret_cast<const bf16x8*>(&xs_l[br][fb]);
            acc[t] = __builtin_amdgcn_mfma_f32_16x16x32_bf16(ah, bh, acc[t], 0, 0, 0);
            acc[t] = __builtin_amdgcn_mfma_f32_16x16x32_bf16(al, bh, acc[t], 0, 0, 0);
            acc[t] = __builtin_amdgcn_mfma_f32_16x16x32_bf16(ah, bl, acc[t], 0, 0, 0);
        }
    }

    const int krow = kb0 + (w << 4) + (lg4 << 2);
    #pragma unroll
    for (int t = 0; t < 16; ++t)
        #pragma unroll
        for (int rr = 0; rr < 4; ++rr)
            atomicAdd(&c_num[(size_t)(krow + rr) * DD + (t << 4) + lx], acc[t][rr]);
}

// ---- legacy fp32 accum (fallback when ws too small for xT)
__global__ __launch_bounds__(256) void accum_kernel(
    const float* __restrict__ r, const float* __restrict__ x,
    float* __restrict__ c_num, int N)
{
    __shared__ float rs[32][65];
    __shared__ float xs2[32][65];
    const int tid = threadIdx.x;
    const int tx = tid & 15, ty = tid >> 4;
    const int tile = blockIdx.x & 15;
    const int chunk = blockIdx.x >> 4;
    const int k0 = (tile >> 2) * 64;
    const int d0 = (tile & 3) * 64;
    const int n0 = chunk * CHUNK;
    const int nend = min(n0 + CHUNK, N);

    float acc[4][4];
    #pragma unroll
    for (int i = 0; i < 4; ++i)
        #pragma unroll
        for (int j = 0; j < 4; ++j) acc[i][j] = 0.f;

    for (int n = n0; n < nend; n += 32) {
        #pragma unroll
        for (int s = 0; s < 2; ++s) {
            int idx = s * 256 + tid;
            int rr = idx >> 4, c4 = (idx & 15) << 2;
            int gn = n + rr;
            float4 rv = make_float4(0.f,0.f,0.f,0.f), xv = make_float4(0.f,0.f,0.f,0.f);
            if (gn < nend) {
                rv = *reinterpret_cast<const float4*>(r + (size_t)gn * KK + k0 + c4);
                xv = *reinterpret_cast<const float4*>(x + (size_t)gn * DD + d0 + c4);
            }
            rs [rr][c4+0]=rv.x; rs [rr][c4+1]=rv.y; rs [rr][c4+2]=rv.z; rs [rr][c4+3]=rv.w;
            xs2[rr][c4+0]=xv.x; xs2[rr][c4+1]=xv.y; xs2[rr][c4+2]=xv.z; xs2[rr][c4+3]=xv.w;
        }
        __syncthreads();
        #pragma unroll 4
        for (int nn = 0; nn < 32; ++nn) {
            float rv[4], xv[4];
            #pragma unroll
            for (int i = 0; i < 4; ++i) rv[i] = rs[nn][ty*4 + i];
            #pragma unroll
            for (int j = 0; j < 4; ++j) xv[j] = xs2[nn][tx + 16*j];
            #pragma unroll
            for (int i = 0; i < 4; ++i)
                #pragma unroll
                for (int j = 0; j < 4; ++j) acc[i][j] += rv[i] * xv[j];
        }
        __syncthreads();
    }
    #pragma unroll
    for (int i = 0; i < 4; ++i)
        #pragma unroll
        for (int j = 0; j < 4; ++j)
            atomicAdd(&c_num[(size_t)(k0 + ty*4 + i) * DD + d0 + tx + 16*j], acc[i][j]);
}

// ---- fused: update + commit + csplit + ccn.  One block per centroid row.
__global__ __launch_bounds__(256) void fusedupd_kernel(
    const float* __restrict__ c_num, const float* __restrict__ w,
    float* __restrict__ c_cur, ushort* __restrict__ c_h, ushort* __restrict__ c_l,
    float* __restrict__ ccn, float* __restrict__ shift2, const int* __restrict__ done)
{
    const int row = blockIdx.x, t = threadIdx.x;
    const int idx = row * DD + t;
    const float wk = w[row] + 1e-8f;
    const float nc = c_num[idx] / wk;
    const float co = c_cur[idx];
    const float d = nc - co;
    const bool dn = (*done) != 0;
    const float cc = dn ? co : nc;
    c_cur[idx] = cc;
    ushort h, lo; split2(cc, h, lo);
    c_h[idx] = h; c_l[idx] = lo;

    float s1 = d * d, s2 = cc * cc;
    #pragma unroll
    for (int m = 32; m >= 1; m >>= 1) { s1 += __shfl_xor(s1, m); s2 += __shfl_xor(s2, m); }
    __shared__ float red1[4], red2[4];
    const int lane = t & 63, wv = t >> 6;
    if (lane == 0) { red1[wv] = s1; red2[wv] = s2; }
    __syncthreads();
    if (t == 0) {
        atomicAdd(shift2, red1[0] + red1[1] + red1[2] + red1[3]);
        ccn[row] = red2[0] + red2[1] + red2[2] + red2[3];
    }
}

// ---- done |= (shift < EPS); reset shift accumulator
__global__ void flag_kernel(float* shift2, int* done) {
    if (sqrtf(*shift2) < 1e-5f) *done = 1;
    *shift2 = 0.f;
}

// ---- final: x@c^T (MFMA) -> logits/0.243 + gumbel -> softmax -> y
__global__ __launch_bounds__(256) void final_mfma(
    const float* __restrict__ x, const ushort* __restrict__ c_h,
    const ushort* __restrict__ c_l, const float* __restrict__ xx,
    const float* __restrict__ ccn, const float* __restrict__ log_tau,
    const float* __restrict__ unif, float* __restrict__ y, int N)
{
    __shared__ ushort xs_h[64][40], xs_l[64][40];
    __shared__ ushort cs_h[256][40], cs_l[256][40];

    const int tid = threadIdx.x;
    const int w = tid >> 6, l = tid & 63;
    const int lx = l & 15, lg4 = l >> 4;
    const int r0 = blockIdx.x * 64;

    f32x4 acc[16];
    #pragma unroll
    for (int t = 0; t < 16; ++t) acc[t] = (f32x4){0.f, 0.f, 0.f, 0.f};

    for (int kk = 0; kk < DD; kk += 32) {
        __syncthreads();
        #pragma unroll
        for (int s = 0; s < 2; ++s) {
            int idx = s * 256 + tid;
            int rr = idx >> 3, c4 = (idx & 7) << 2;
            int gr = r0 + rr;
            float4 v = make_float4(0.f, 0.f, 0.f, 0.f);
            if (gr < N) v = *reinterpret_cast<const float4*>(x + (size_t)gr * DD + kk + c4);
            ushort h0,l0,h1,l1,h2,l2,h3,l3;
            split2(v.x, h0, l0); split2(v.y, h1, l1);
            split2(v.z, h2, l2); split2(v.w, h3, l3);
            *reinterpret_cast<ushort4*>(&xs_h[rr][c4]) = make_ushort4(h0, h1, h2, h3);
            *reinterpret_cast<ushort4*>(&xs_l[rr][c4]) = make_ushort4(l0, l1, l2, l3);
        }
        #pragma unroll
        for (int s = 0; s < 4; ++s) {
            int idx = s * 256 + tid;
            int rr = idx >> 2, c8 = (idx & 3) << 3;
            *reinterpret_cast<ushort8*>(&cs_h[rr][c8]) =
                *reinterpret_cast<const ushort8*>(c_h + (size_t)rr * DD + kk + c8);
            *reinterpret_cast<ushort8*>(&cs_l[rr][c8]) =
                *reinterpret_cast<const ushort8*>(c_l + (size_t)rr * DD + kk + c8);
        }
        __syncthreads();

        const int fb = lg4 << 3;
        const int ar = (w << 4) + lx;
        bf16x8 ah = *reinterpret_cast<const bf16x8*>(&xs_h[ar][fb]);
        bf16x8 al = *reinterpret_cast<const bf16x8*>(&xs_l[ar][fb]);
        #pragma unroll
        for (int t = 0; t < 16; ++t) {
            const int br = (t << 4) + lx;
            bf16x8 bh = *reinterpret_cast<const bf16x8*>(&cs_h[br][fb]);
            bf16x8 bl = *reinterpret_cast<const bf16x8*>(&cs_l[br][fb]);
            acc[t] = __builtin_amdgcn_mfma_f32_16x16x32_bf16(ah, bh, acc[t], 0, 0, 0);
            acc[t] = __builtin_amdgcn_mfma_f32_16x16x32_bf16(al, bh, acc[t], 0, 0, 0);
            acc[t] = __builtin_amdgcn_mfma_f32_16x16x32_bf16(ah, bl, acc[t], 0, 0, 0);
        }
    }

    const float tau = expf(log_tau[0]);
    float ccv[16];
    #pragma unroll
    for (int t = 0; t < 16; ++t) ccv[t] = ccn[(t << 4) + lx];

    #pragma unroll
    for (int rr = 0; rr < 4; ++rr) {
        const int gr = r0 + (w << 4) + (lg4 << 2) + rr;
        const bool valid = gr < N;
        const float xxv = valid ? xx[gr] : 0.f;
        float z[16], m = -1e30f;
        #pragma unroll
        for (int t = 0; t < 16; ++t) {
            float d2 = xxv + ccv[t] - 2.f * acc[t][rr];
            float lgt = -d2 / tau;
            float u = valid ? unif[(size_t)gr * KK + (t << 4) + lx] : 0.5f;
            float g = -logf(-logf(u));
            z[t] = lgt / 0.243f + g;
            m = fmaxf(m, z[t]);
        }
        #pragma unroll
        for (int mk = 8; mk >= 1; mk >>= 1) m = fmaxf(m, __shfl_xor(m, mk));
        float es = 0.f;
        #pragma unroll
        for (int t = 0; t < 16; ++t) { z[t] = __expf(z[t] - m); es += z[t]; }
        #pragma unroll
        for (int mk = 8; mk >= 1; mk >>= 1) es += __shfl_xor(es, mk);
        const float rinv = 1.f / es;
        if (valid) {
            #pragma unroll
            for (int t = 0; t < 16; ++t)
                y[(size_t)gr * KK + (t << 4) + lx] = z[t] * rinv;
        }
    }
}

extern "C" void kernel_launch(void* const* d_in, const int* in_sizes, int n_in,
                              void* d_out, int out_size, void* d_ws, size_t ws_size,
                              hipStream_t stream)
{
    const float* x       = (const float*)d_in[0];
    const float* c_in    = (const float*)d_in[1];
    const float* log_tau = (const float*)d_in[2];
    const float* unif    = (const float*)d_in[3];
    float* y = (float*)d_out;
    const int N = in_sizes[0] / DD;
    const int NPAD = ((N + 63) / 64) * 64;

    float* ws = (float*)d_ws;
    size_t off = 0;
    float* xx     = ws + off; off += (size_t)NPAD;
    float* ccn    = ws + off; off += KK;
    float* c_cur  = ws + off; off += (size_t)KK * DD;
    float* c_num  = ws + off; off += (size_t)KK * DD;
    float* w      = ws + off; off += KK;                // MUST follow c_num (one memset)
    float* shift2 = ws + off; off += 1;
    int*   done   = (int*)(ws + off); off += 1;
    ushort* c_h   = (ushort*)(ws + off); off += (size_t)KK * DD / 2;
    ushort* c_l   = (ushort*)(ws + off); off += (size_t)KK * DD / 2;
    ushort* xT_h  = (ushort*)(ws + off); off += (size_t)DD * NPAD / 2;
    ushort* xT_l  = (ushort*)(ws + off); off += (size_t)DD * NPAD / 2;
    const bool full = ws_size >= off * sizeof(float);

    hipMemsetAsync(shift2, 0, 2 * sizeof(float), stream);   // shift2 + done
    hipMemcpyAsync(c_cur, c_in, (size_t)KK * DD * sizeof(float),
                   hipMemcpyDeviceToDevice, stream);
    rowsq_kernel<<<(N + 3) / 4, 256, 0, stream>>>(x, xx, N);
    if (full) xtrans_kernel<<<NPAD / 64, 256, 0, stream>>>(x, xT_h, xT_l, N, NPAD);
    csplit_kernel<<<KK / 4, 256, 0, stream>>>(c_cur, c_h, c_l, ccn);

    const int nblk = (N + 63) / 64;
    const int nch  = (N + 383) / 384;
    const int nch_old = (N + CHUNK - 1) / CHUNK;
    for (int it = 0; it < 10; ++it) {
        hipMemsetAsync(c_num, 0, (size_t)(KK * DD + KK) * sizeof(float), stream);
        assign_mfma<<<nblk, 256, 0, stream>>>(x, c_h, c_l, xx, ccn, log_tau, y, w, N);
        if (full)
            accum_mfma<<<4 * nch, 256, 0, stream>>>(y, xT_h, xT_l, c_num, N, NPAD);
        else
            accum_kernel<<<16 * nch_old, 256, 0, stream>>>(y, x, c_num, N);
        fusedupd_kernel<<<KK, 256, 0, stream>>>(c_num, w, c_cur, c_h, c_l, ccn, shift2, done);
        flag_kernel<<<1, 1, 0, stream>>>(shift2, done);
    }
    final_mfma<<<nblk, 256, 0, stream>>>(x, c_h, c_l, xx, ccn, log_tau, unif, y, N);
}